// Round 7
// baseline (1935.668 us; speedup 1.0000x reference)
//
#include <hip/hip_runtime.h>
#include <hip/hip_bf16.h>

#define T_LEN 256
#define B_DIM 128
#define I_DIM 256
#define H_DIM 1024

typedef __attribute__((ext_vector_type(8))) short short8;
typedef __attribute__((ext_vector_type(4))) float f32x4;

// Sync words: g_sync[bq*64 + lj*2 + mt] = subflag of (block lj, m-tile wave mt)
// in cluster bq. Monotonic step counts; clusters 256B apart.
// Re-zeroed by init_hT0 every call/replay.
__device__ unsigned g_sync[256];

// RNE float->bf16 (self-contained; inputs here are never NaN)
static __device__ __forceinline__ unsigned short f2bf(float f) {
  unsigned u = __float_as_uint(f);
  return (unsigned short)((u + 0x7fffu + ((u >> 16) & 1u)) >> 16);
}
static __device__ __forceinline__ float bf2f(unsigned short h) {
  return __uint_as_float((unsigned)h << 16);
}

// ---------------------------------------------------------------------------
// Phase 1a (fallback): x_proj GEMM fp32 (proven, used when ws is small).
// ---------------------------------------------------------------------------
__global__ __launch_bounds__(256) void xproj_gemm(
    const float* __restrict__ A, const float* __restrict__ W,
    const float* __restrict__ bias, float* __restrict__ C) {
  __shared__ float As[64][33];
  __shared__ float Ws[64][33];

  const int tid = threadIdx.x;
  const int m0 = blockIdx.y * 64;
  const int n0 = blockIdx.x * 64;
  const int ty = tid >> 4;
  const int tx = tid & 15;
  const int r   = tid >> 3;
  const int c4  = (tid & 7) << 2;

  float acc[4][4] = {};

  for (int kc = 0; kc < I_DIM; kc += 32) {
#pragma unroll
    for (int p = 0; p < 2; ++p) {
      const int rr = r + p * 32;
      const float4 a = *(const float4*)(A + (size_t)(m0 + rr) * I_DIM + kc + c4);
      As[rr][c4 + 0] = a.x; As[rr][c4 + 1] = a.y;
      As[rr][c4 + 2] = a.z; As[rr][c4 + 3] = a.w;
      const float4 w = *(const float4*)(W + (size_t)(n0 + rr) * I_DIM + kc + c4);
      Ws[rr][c4 + 0] = w.x; Ws[rr][c4 + 1] = w.y;
      Ws[rr][c4 + 2] = w.z; Ws[rr][c4 + 3] = w.w;
    }
    __syncthreads();
#pragma unroll
    for (int k = 0; k < 32; ++k) {
      float av[4], wv[4];
#pragma unroll
      for (int i = 0; i < 4; ++i) av[i] = As[ty * 4 + i][k];
#pragma unroll
      for (int j = 0; j < 4; ++j) wv[j] = Ws[tx * 4 + j][k];
#pragma unroll
      for (int i = 0; i < 4; ++i)
#pragma unroll
        for (int j = 0; j < 4; ++j)
          acc[i][j] = fmaf(av[i], wv[j], acc[i][j]);
    }
    __syncthreads();
  }

  const float4 bv = *(const float4*)(bias + n0 + tx * 4);
#pragma unroll
  for (int i = 0; i < 4; ++i) {
    float4 o;
    o.x = acc[i][0] + bv.x;
    o.y = acc[i][1] + bv.y;
    o.z = acc[i][2] + bv.z;
    o.w = acc[i][3] + bv.w;
    *(float4*)(C + (size_t)(m0 + ty * 4 + i) * H_DIM + n0 + tx * 4) = o;
  }
}

// ---------------------------------------------------------------------------
// Phase 1b: x_proj via split-bf16 MFMA (r6-proven, absmax unchanged).
// ---------------------------------------------------------------------------
__global__ __launch_bounds__(256) void cvt_hi_lo(
    const float* __restrict__ X, unsigned short* __restrict__ Xh,
    unsigned short* __restrict__ Xl) {
  const int i4 = blockIdx.x * 256 + threadIdx.x;     // one float4 per thread
  const float4 x = ((const float4*)X)[i4];
  ushort4 h, l;
  h.x = f2bf(x.x); l.x = f2bf(x.x - bf2f(h.x));
  h.y = f2bf(x.y); l.y = f2bf(x.y - bf2f(h.y));
  h.z = f2bf(x.z); l.z = f2bf(x.z - bf2f(h.z));
  h.w = f2bf(x.w); l.w = f2bf(x.w - bf2f(h.w));
  ((ushort4*)Xh)[i4] = h;
  ((ushort4*)Xl)[i4] = l;
}

__global__ __launch_bounds__(256) void xproj_mfma(
    const unsigned short* __restrict__ Ah, const unsigned short* __restrict__ Al,
    const unsigned short* __restrict__ Wh, const unsigned short* __restrict__ Wl,
    const float* __restrict__ bias, float* __restrict__ C) {
  const int tid  = threadIdx.x;
  const int wv   = tid >> 6;
  const int lane = tid & 63;
  const int ln   = lane & 15;
  const int q    = lane >> 4;
  const int mw   = wv >> 1;                 // 0..1
  const int nw   = wv & 1;                  // 0..1
  const int m0   = blockIdx.y * 128 + mw * 64;
  const int n0   = blockIdx.x * 64  + nw * 32;

  f32x4 acc[4][2] = {};

#pragma unroll
  for (int kc = 0; kc < 8; ++kc) {          // K = 256 = 8 x 32
    const int ko = kc * 32 + q * 8;
    short8 afh[4], afl[4], wfh[2], wfl[2];
#pragma unroll
    for (int fm = 0; fm < 4; ++fm) {
      const size_t off = (size_t)(m0 + fm * 16 + ln) * I_DIM + ko;
      afh[fm] = *(const short8*)(Ah + off);
      afl[fm] = *(const short8*)(Al + off);
    }
#pragma unroll
    for (int fn = 0; fn < 2; ++fn) {
      const size_t off = (size_t)(n0 + fn * 16 + ln) * I_DIM + ko;
      wfh[fn] = *(const short8*)(Wh + off);
      wfl[fn] = *(const short8*)(Wl + off);
    }
#pragma unroll
    for (int fm = 0; fm < 4; ++fm)
#pragma unroll
      for (int fn = 0; fn < 2; ++fn) {
        acc[fm][fn] = __builtin_amdgcn_mfma_f32_16x16x32_bf16(afh[fm], wfh[fn], acc[fm][fn], 0, 0, 0);
        acc[fm][fn] = __builtin_amdgcn_mfma_f32_16x16x32_bf16(afh[fm], wfl[fn], acc[fm][fn], 0, 0, 0);
        acc[fm][fn] = __builtin_amdgcn_mfma_f32_16x16x32_bf16(afl[fm], wfh[fn], acc[fm][fn], 0, 0, 0);
      }
  }

  // D layout: col (j) = lane&15, row (m) = (lane>>4)*4 + reg.
#pragma unroll
  for (int fn = 0; fn < 2; ++fn) {
    const int j = n0 + fn * 16 + ln;
    const float bj = bias[j];
#pragma unroll
    for (int fm = 0; fm < 4; ++fm)
#pragma unroll
      for (int r = 0; r < 4; ++r)
        C[(size_t)(m0 + fm * 16 + q * 4 + r) * H_DIM + j] = acc[fm][fn][r] + bj;
  }
}

// ---------------------------------------------------------------------------
// One-time converts: W_hh -> bf16 [j][k]; hT0 -> bf16 broadcast of h0.
// init_hT0 also re-zeroes the sync flags.
// ---------------------------------------------------------------------------
__global__ __launch_bounds__(256) void cvt_w_bf16(
    const float* __restrict__ W, unsigned short* __restrict__ Wb) {
  const int i4 = blockIdx.x * 256 + threadIdx.x;
  const float4 w = ((const float4*)W)[i4];
  ushort4 o;
  o.x = f2bf(w.x); o.y = f2bf(w.y); o.z = f2bf(w.z); o.w = f2bf(w.w);
  ((ushort4*)Wb)[i4] = o;
}

__global__ __launch_bounds__(256) void init_hT0(
    const float* __restrict__ h0, unsigned short* __restrict__ hT) {
  const int idx = blockIdx.x * 256 + threadIdx.x;    // [0, 131072)
  hT[idx] = f2bf(h0[idx & (H_DIM - 1)]);
  if (blockIdx.x == 0) g_sync[threadIdx.x] = 0u;
}

// ---------------------------------------------------------------------------
// Phase 2: persistent cooperative kernel. Grid 128 = 32 j-tiles (32 j) x 4
// b-quarter clusters. Block = 4 waves: wave w -> m-tile (w&1) x k-half (w>>1).
//
// Round-7 restructure (r6 showed VGPR=124 -> wfrag was SPILLED to scratch
// every step; and barrier-stage-count changes were neutral):
//  - W_hh slice lives in LDS (64 KB, staged once, lane-linear conflict-free
//    ds_read_b128). No VGPR pressure, no scratch, no coherence traffic.
//  - ONE __syncthreads per step: red[] double-buffered by t&1; the second
//    barrier replaced by per-m-tile SUBFLAGS: waves 0,1 each drain their own
//    stores (s_waitcnt vmcnt(0)) and post flag[lj*2+mt] = t+1.
//  - Consumer wave (mt,kh) polls exactly its 16 producer subflags
//    (blocks kh*16..+16, subflag mt). Union over the block's 4 waves =
//    all 32 blocks x both subflags, joined by the barrier BEFORE the
//    epilogue -> ping-pong overwrite still safe.
//  - x_proj[t+1] prefetched one step ahead via inline-asm loads + counted
//    s_waitcnt vmcnt(8) (16 h-loads issued first = oldest drain first), so
//    its HBM latency hides under a full step and never blocks the poll.
//  - Flag posted BEFORE the fp32 xio stores (nobody depends on them).
// Coherence (r4-r6 proven): h via WT relaxed-agent stores + sc0sc1 loads;
// no cache maintenance anywhere.
// ---------------------------------------------------------------------------
__global__ __launch_bounds__(256, 1) void rnn_persist(
    unsigned short* __restrict__ hT,            // ping-pong; parity0 = bf16(h0)
    const unsigned short* __restrict__ Wb,      // [1024][1024] bf16
    const float* __restrict__ b_hh,
    const float* __restrict__ h0,
    float* __restrict__ out)                    // [T][B][H]: in x_proj, out h_t
{
  __shared__ short8 w_lds[2 * 2 * 16 * 64];     // 64 KB: [kh][jf][kc][lane]
  __shared__ float red[2][2][16][33];           // [t&1][mt][b_local][j_local]

  const int tid  = threadIdx.x;
  const int wv   = tid >> 6;
  const int lane = tid & 63;
  const int ln   = lane & 15;        // A: b-row / B: j-row / D: j-col
  const int q    = lane >> 4;        // 0..3

  const int bid = blockIdx.x;
  const int bq  = bid >> 5;          // cluster (batch quarter)
  const int lj  = bid & 31;          // j-tile within cluster
  const int j0  = lj * 32;
  const int mt  = wv & 1;            // m-tile within the 32-b quarter
  const int kh  = wv >> 1;           // k-half
  const int b0  = bq * 32 + mt * 16;

  // ---- stage W slice into LDS (once): wave w fills quadrant (kh_f, jf_f).
  {
    const int kh_f = wv >> 1, jf_f = wv & 1;
    const short8* __restrict__ src =
        (const short8*)(Wb + (size_t)(j0 + jf_f * 16 + ln) * H_DIM + kh_f * 512 + q * 8);
    short8* dst = &w_lds[((kh_f * 2 + jf_f) * 16) * 64 + lane];
#pragma unroll
    for (int kc = 0; kc < 16; ++kc) dst[kc * 64] = src[kc * 4];
  }

  const size_t HT = (size_t)B_DIM * H_DIM;     // 131072
  const size_t arow = (size_t)(b0 + ln) * H_DIM + kh * 512 + q * 8;
  const unsigned short* __restrict__ ha0 = hT + arow;
  const unsigned short* __restrict__ ha1 = hT + HT + arow;

  float bj[2];
#pragma unroll
  for (int jf = 0; jf < 2; ++jf) bj[jf] = b_hh[j0 + jf * 16 + ln];

  const size_t obase = (size_t)(b0 + q * 4) * H_DIM + j0 + ln;

  float hcur[2][4];
#pragma unroll
  for (int jf = 0; jf < 2; ++jf) {
    const float h0j = h0[j0 + jf * 16 + ln];
#pragma unroll
    for (int r = 0; r < 4; ++r) hcur[jf][r] = h0j;
  }

  // Poll target: subflag mt of producer blocks kh*16 + (lane&15).
  unsigned* pollp  = &g_sync[bq * 64 + kh * 32 + ((lane & 15) << 1) + mt];
  unsigned* myflag = &g_sync[bq * 64 + (lj << 1) + mt];   // posted by wv<2

  // x_proj[0] preload (wv<2).
  float xcur[2][4];
  if (wv < 2) {
#pragma unroll
    for (int jf = 0; jf < 2; ++jf)
#pragma unroll
      for (int r = 0; r < 4; ++r)
        xcur[jf][r] = out[obase + (size_t)r * H_DIM + jf * 16];
  }
  asm volatile("s_waitcnt vmcnt(0)" ::: "memory");  // exact vmcnt bookkeeping
  __syncthreads();                                  // W staging complete

  for (int t = 0; t < T_LEN; ++t) {
    // ---- wait for this wave's 16 producer subflags (t>0) ----
    if (t > 0) {
      const unsigned tgt = (unsigned)t;
      for (;;) {
        unsigned fv;
        asm volatile("global_load_dword %0, %1, off sc0 sc1\n\t"
                     "s_waitcnt vmcnt(0)"
                     : "=v"(fv) : "v"(pollp) : "memory");
        if (__all((int)fv >= (int)tgt)) break;
        __builtin_amdgcn_s_sleep(2);
      }
    }
    __builtin_amdgcn_sched_barrier(0);

    // ---- h fragments: 16 coherent 16B loads (issued first = oldest) ----
    const unsigned short* __restrict__ ha = (t & 1) ? ha1 : ha0;
    short8 hfrag[16];
#pragma unroll
    for (int kc = 0; kc < 16; ++kc) {
      asm volatile("global_load_dwordx4 %0, %1, off offset:%2 sc0 sc1"
                   : "=&v"(hfrag[kc]) : "v"(ha), "i"(kc * 64));
    }

    // ---- x_proj[t+1] prefetch (wv<2): 8 cached loads, then counted wait:
    // vmcnt(8) -> all 16 h-loads done, 8 x-loads still in flight.
    float xnext[2][4];
    if (wv < 2) {
      const int tn = (t + 1 < T_LEN) ? t + 1 : T_LEN - 1;
      const float* __restrict__ xnp = out + (size_t)tn * HT;
#pragma unroll
      for (int jf = 0; jf < 2; ++jf)
#pragma unroll
        for (int r = 0; r < 4; ++r) {
          const float* p = xnp + obase + (size_t)r * H_DIM + jf * 16;
          asm volatile("global_load_dword %0, %1, off"
                       : "=&v"(xnext[jf][r]) : "v"(p));
        }
      asm volatile("s_waitcnt vmcnt(8)" ::: "memory");
    } else {
      asm volatile("s_waitcnt vmcnt(0)" ::: "memory");
    }
    __builtin_amdgcn_sched_barrier(0);   // rule #18

    // ---- MFMA: 2 j-subtiles x 16 k-chunks, W from LDS (conflict-free) ----
    f32x4 a0[2], a1[2];
#pragma unroll
    for (int jf = 0; jf < 2; ++jf) { a0[jf] = (f32x4){0,0,0,0}; a1[jf] = (f32x4){0,0,0,0}; }
#pragma unroll
    for (int kc = 0; kc < 16; kc += 2) {
#pragma unroll
      for (int jf = 0; jf < 2; ++jf) {
        const short8 w0 = w_lds[((kh * 2 + jf) * 16 + kc) * 64 + lane];
        const short8 w1 = w_lds[((kh * 2 + jf) * 16 + kc + 1) * 64 + lane];
        a0[jf] = __builtin_amdgcn_mfma_f32_16x16x32_bf16(hfrag[kc],     w0, a0[jf], 0, 0, 0);
        a1[jf] = __builtin_amdgcn_mfma_f32_16x16x32_bf16(hfrag[kc + 1], w1, a1[jf], 0, 0, 0);
      }
    }
    f32x4 acc[2];
#pragma unroll
    for (int jf = 0; jf < 2; ++jf) acc[jf] = a0[jf] + a1[jf];

    // D layout: j_col = lane&15, b_row = (lane>>4)*4 + reg.
    if (wv >= 2) {
#pragma unroll
      for (int jf = 0; jf < 2; ++jf)
#pragma unroll
        for (int r = 0; r < 4; ++r)
          red[t & 1][mt][q * 4 + r][jf * 16 + ln] = acc[jf][r];
    }
    __syncthreads();   // the ONLY barrier: joins k-half partials AND all
                       // 4 waves' polls (ping-pong safety) each step.
    if (wv < 2) {
      unsigned short* __restrict__ hnext = hT + (size_t)((t + 1) & 1) * HT;
      float* __restrict__ xio_t = out + (size_t)t * HT;
      float v[2][4];
#pragma unroll
      for (int jf = 0; jf < 2; ++jf)
#pragma unroll
        for (int r = 0; r < 4; ++r) {
          const float rec = acc[jf][r] + red[t & 1][mt][q * 4 + r][jf * 16 + ln];
          float x = 0.9f * hcur[jf][r] + 0.1f * (rec + bj[jf] + xcur[jf][r]);
          x = x > 0.f ? x : 0.f;
          v[jf][r] = x;
          hcur[jf][r] = x;
          // h state first: WT relaxed-agent -> at coherence once vmcnt retires.
          __hip_atomic_store(&hnext[obase + (size_t)r * H_DIM + jf * 16],
                             f2bf(x), __ATOMIC_RELAXED, __HIP_MEMORY_SCOPE_AGENT);
        }
      // Drain OWN wave's h-stores (+ leftover x-prefetch), then post subflag.
      asm volatile("s_waitcnt vmcnt(0)" ::: "memory");
      __builtin_amdgcn_sched_barrier(0);
      if ((tid & 63) == 0)
        __hip_atomic_store(myflag, (unsigned)(t + 1), __ATOMIC_RELAXED,
                           __HIP_MEMORY_SCOPE_AGENT);
      // fp32 output stores off the critical path (drained by next poll).
#pragma unroll
      for (int jf = 0; jf < 2; ++jf)
#pragma unroll
        for (int r = 0; r < 4; ++r)
          xio_t[obase + (size_t)r * H_DIM + jf * 16] = v[jf][r];
      // rotate the x prefetch
#pragma unroll
      for (int jf = 0; jf < 2; ++jf)
#pragma unroll
        for (int r = 0; r < 4; ++r) xcur[jf][r] = xnext[jf][r];
    }
  }
}

// ---------------------------------------------------------------------------
extern "C" void kernel_launch(void* const* d_in, const int* in_sizes, int n_in,
                              void* d_out, int out_size, void* d_ws, size_t ws_size,
                              hipStream_t stream) {
  const float* input = (const float*)d_in[0];
  const float* W_in  = (const float*)d_in[1];
  const float* b_in  = (const float*)d_in[2];
  const float* W_hh  = (const float*)d_in[3];
  const float* b_hh  = (const float*)d_in[4];
  const float* h0    = (const float*)d_in[5];
  float* out = (float*)d_out;

  // ws layout (bytes):
  //   [0,  2M)   Wb   bf16 [1024][1024]
  //   [2M, 2.5M) hT   ping-pong 2 x 256 KB
  //   [2.5M,3M)  Wih  bf16-hi W_in ; [3M,3.5M) Wil bf16-lo
  //   [4M, 20M)  Ah   bf16-hi input ; [20M,36M) Al bf16-lo
  char* ws = (char*)d_ws;
  unsigned short* Wb  = (unsigned short*)ws;
  unsigned short* hT  = (unsigned short*)(ws + (2u << 20));
  unsigned short* Wih = (unsigned short*)(ws + (5u << 19));
  unsigned short* Wil = (unsigned short*)(ws + (3u << 20));
  unsigned short* Ah  = (unsigned short*)(ws + (4u << 20));
  unsigned short* Al  = (unsigned short*)(ws + (20u << 20));

  cvt_w_bf16<<<(H_DIM * H_DIM / 4) / 256, 256, 0, stream>>>(W_hh, Wb);
  init_hT0<<<(B_DIM * H_DIM) / 256, 256, 0, stream>>>(h0, hT);

  if (ws_size >= (36u << 20)) {
    cvt_hi_lo<<<(T_LEN * B_DIM * I_DIM / 4) / 256, 256, 0, stream>>>(input, Ah, Al);
    cvt_hi_lo<<<(H_DIM * I_DIM / 4) / 256, 256, 0, stream>>>(W_in, Wih, Wil);
    dim3 g1(H_DIM / 64, (T_LEN * B_DIM) / 128);
    xproj_mfma<<<g1, 256, 0, stream>>>(Ah, Al, Wih, Wil, b_in, out);
  } else {
    dim3 g1(H_DIM / 64, (T_LEN * B_DIM) / 64);
    xproj_gemm<<<g1, 256, 0, stream>>>(input, W_in, b_in, out);
  }

  {
    unsigned short* hT_ = hT;
    const unsigned short* Wb_ = Wb;
    const float* bhh_ = b_hh;
    const float* h0_ = h0;
    float* out_ = out;
    void* pargs[5] = {(void*)&hT_, (void*)&Wb_, (void*)&bhh_, (void*)&h0_, (void*)&out_};
    hipLaunchCooperativeKernel((const void*)rnn_persist, dim3(128), dim3(256),
                               pargs, 0, stream);
  }
}